// Round 9
// baseline (227.102 us; speedup 1.0000x reference)
//
#include <hip/hip_runtime.h>
#include <hip/hip_bf16.h>
#include <stdint.h>

#define DIMF   1024
#define HEADS  16
#define HD     64
#define BB     2
#define NN     2048
#define NKP    2112   // 2049 keys padded to 33*64
#define NTILE  33

typedef __attribute__((ext_vector_type(8))) __bf16 bf16x8;
typedef __attribute__((ext_vector_type(4))) float  f32x4;

__device__ __forceinline__ float b2f(uint16_t h) {
  union { uint32_t u; float f; } v; v.u = ((uint32_t)h) << 16; return v.f;
}
__device__ __forceinline__ uint16_t f2b(float f) {
  union { float f; uint32_t u; } v; v.f = f;
  uint32_t r = v.u + 0x7FFFu + ((v.u >> 16) & 1u);
  return (uint16_t)(r >> 16);
}
// packed f32x2 -> bf16x2 via the COMPILER intrinsic (operand order guaranteed)
__device__ __forceinline__ uint32_t pack2(float a, float b) {
  __hip_bfloat162 h = __float22bfloat162_rn(float2{a, b});
  union { __hip_bfloat162 h; uint32_t u; } v; v.h = h; return v.u;
}

// async global->LDS DMA, 16B per lane. LDS dest = wave-uniform base + lane*16.
__device__ __forceinline__ void gl_lds16(const void* g, void* l) {
  __builtin_amdgcn_global_load_lds(
      (const __attribute__((address_space(1))) void*)g,
      (__attribute__((address_space(3))) void*)l, 16, 0, 0);
}

// ---------------- fp32 -> bf16 bulk convert (float4 loads) ----------------
__global__ __launch_bounds__(256) void cvt_f32_bf16(const float* __restrict__ src,
                                                    uint16_t* __restrict__ dst, int n4) {
  int i = blockIdx.x * 256 + threadIdx.x;
  if (i < n4) {
    float4 v = *(const float4*)&src[i * 4];
    uint16_t* d = dst + i * 4;
    d[0] = f2b(v.x); d[1] = f2b(v.y); d[2] = f2b(v.z); d[3] = f2b(v.w);
  }
}

// -------- transpose + convert (fp32 M x N -> bf16 N x M), 32x32 tiles --------
__global__ __launch_bounds__(256) void transpose_k(const float* __restrict__ src,
                                                   uint16_t* __restrict__ dst, int M, int N) {
  __shared__ uint16_t tile[32][33];
  int bx = blockIdx.x * 32, by = blockIdx.y * 32;
  int x = threadIdx.x, y0 = threadIdx.y;
#pragma unroll
  for (int i = 0; i < 32; i += 8)
    tile[y0 + i][x] = f2b(src[(size_t)(by + y0 + i) * N + bx + x]);
  __syncthreads();
#pragma unroll
  for (int i = 0; i < 32; i += 8)
    dst[(size_t)(bx + y0 + i) * M + by + x] = tile[x][y0 + i];
}

// ---------------- fill void K/V rows + zero padding ----------------
__global__ __launch_bounds__(256) void fill_void(const float* __restrict__ vk,
                                                 const float* __restrict__ vv,
                                                 uint16_t* __restrict__ k_ws,
                                                 uint16_t* __restrict__ vt_ws) {
  int idx = blockIdx.x * 256 + threadIdx.x;   // 0 .. 131071 = BB*HEADS*64*64
  int dd = idx & 63;
  int r  = (idx >> 6) & 63;      // padded key row 2048+r
  int bh = idx >> 12;            // 0..31
  int h  = bh & (HEADS - 1);
  uint16_t kv  = (r == 0) ? f2b(vk[h * HD + dd]) : (uint16_t)0;
  uint16_t vvv = (r == 0) ? f2b(vv[h * HD + dd]) : (uint16_t)0;
  k_ws[((size_t)bh * NKP + NN + r) * HD + dd]  = kv;
  vt_ws[((size_t)bh * HD + dd) * NKP + NN + r] = vvv;
}

// ---------------- GEMM: C[M,N] = A[M,K] * Bt[N,K]^T, bf16 in, fp32 acc ----------------
// EPI 0: scatter bf16 to Q [bh,2048,64] (PRE-SCALED by per-head sl2 = scale*log2e),
//        K [bh,2112,64], Vt [bh,64,2112]
// EPI 1: add fp32 bias, write FP32 row-major [M,Nout] (d_out is float*)
template<int EPI>
__global__ __launch_bounds__(256) void gemm_bt(const uint16_t* __restrict__ A,
                                               const uint16_t* __restrict__ Bt,
                                               int K, int Nout,
                                               uint16_t* __restrict__ o0,
                                               uint16_t* __restrict__ o1,
                                               uint16_t* __restrict__ o2,
                                               float* __restrict__ fo,
                                               const float* __restrict__ bias,
                                               const float* __restrict__ trace,
                                               const float* __restrict__ factor) {
  __shared__ uint16_t lds_a[128][32];   // linear: required by global_load_lds
  __shared__ uint16_t lds_b[128][32];
  const int m0 = blockIdx.y * 128, n0 = blockIdx.x * 128;
  const int tid = threadIdx.x, lane = tid & 63, wid = tid >> 6;
  const int wm = (wid >> 1) * 64, wn = (wid & 1) * 64;
  const int lr = lane & 15, lg = lane >> 4;
  f32x4 acc[4][4] = {};
  for (int k0 = 0; k0 < K; k0 += 32) {
    __syncthreads();
#pragma unroll
    for (int it = 0; it < 2; ++it) {
      const int chunk = wid * 2 + it;            // 0..7 (1 KiB each)
      const int o = chunk * 1024 + lane * 16;
      const int r = o >> 6, cb = o & 63;
      gl_lds16((const char*)&A[(size_t)(m0 + r) * K + k0] + cb,
               (char*)&lds_a[0][0] + chunk * 1024);
      gl_lds16((const char*)&Bt[(size_t)(n0 + r) * K + k0] + cb,
               (char*)&lds_b[0][0] + chunk * 1024);
    }
    __syncthreads();
    bf16x8 af[4], bf[4];
#pragma unroll
    for (int i = 0; i < 4; ++i)
      af[i] = *(const bf16x8*)((const char*)&lds_a[0][0] + (wm + i * 16 + lr) * 64 + lg * 16);
#pragma unroll
    for (int j = 0; j < 4; ++j)
      bf[j] = *(const bf16x8*)((const char*)&lds_b[0][0] + (wn + j * 16 + lr) * 64 + lg * 16);
#pragma unroll
    for (int i = 0; i < 4; ++i)
#pragma unroll
      for (int j = 0; j < 4; ++j)
        acc[i][j] = __builtin_amdgcn_mfma_f32_16x16x32_bf16(af[i], bf[j], acc[i][j], 0, 0, 0);
  }
#pragma unroll
  for (int i = 0; i < 4; ++i)
#pragma unroll
    for (int j = 0; j < 4; ++j)
#pragma unroll
      for (int r = 0; r < 4; ++r) {
        int mg = m0 + wm + i * 16 + lg * 4 + r;   // C row = m (m89 layout)
        int ng = n0 + wn + j * 16 + lr;            // C col = n
        float v = acc[i][j][r];
        if (EPI == 0) {
          int b = mg >> 11, n = mg & (NN - 1);
          int which = ng >> 10, rem = ng & (DIMF - 1), h = rem >> 6, dd = rem & 63;
          int bh = b * HEADS + h;
          float vv = v;
          if (which == 0) {   // Q: fold (dim^-0.5 / temp) * log2(e) into Q
            float tmp = fmaxf(1.0f + fabsf(trace[h]) * factor[h], 1.0f);
            vv = v * (0.04508422f / tmp);          // 0.03125 * 1.44269504
          }
          uint16_t bv = f2b(vv);
          if (which == 0)      o0[((size_t)bh * NN + n) * HD + dd] = bv;
          else if (which == 1) o1[((size_t)bh * NKP + n) * HD + dd] = bv;
          else                 o2[((size_t)bh * HD + dd) * NKP + n] = bv;  // V transposed
        } else {
          fo[(size_t)mg * Nout + ng] = v + bias[ng];   // FP32 output
        }
      }
}

// ---------- flash attention: barrier-free, K/V fragments direct from L2 ----------
// 1 wave/block, 32 q-rows. Swapped QK^T (S^T = mfma(K,Q)), P staged through
// wave-private LDS (round-8-proven relayout), PV = mfma(P, V^T) (round-8-proven).
// K/V per (b,h) = 540 KB; grid is (bh, qb) so XCD = linear%8 = bh%8 -> each XCD
// serves 4 bh = 2.2 MB, L2-resident; same-CU blocks share bh (L1 reuse).
// Q is PRE-SCALED by sl2 in gemm<0>, so p = exp2f(s) directly. Fixed-max softmax
// (|logit*log2e| <= ~3); zero-padded phantom keys give p=1, subtracted at end.
__global__ __launch_bounds__(64) void attn_g(const uint16_t* __restrict__ q_ws,
                                             const uint16_t* __restrict__ k_ws,
                                             const uint16_t* __restrict__ vt_ws,
                                             uint16_t* __restrict__ o_ws) {
  __shared__ uint16_t ldsp[2][16][72];   // [qhalf][q][key(+pad)]
  const int bh = blockIdx.x;             // b*HEADS + h
  const int qb = blockIdx.y;
  const int h = bh & (HEADS - 1), b = bh >> 4;
  const int lane = threadIdx.x;
  const int lr = lane & 15, lg = lane >> 4;

  const int qrow0 = qb * 32;
  const uint16_t* qpa = q_ws + ((size_t)bh * NN + qrow0 + lr) * HD;
  const uint16_t* qpb = qpa + 16 * HD;
  bf16x8 qfa[2], qfb[2];
#pragma unroll
  for (int kk = 0; kk < 2; ++kk) {
    qfa[kk] = *(const bf16x8*)(qpa + kk * 32 + lg * 8);
    qfb[kk] = *(const bf16x8*)(qpb + kk * 32 + lg * 8);
  }

  const uint16_t* kb = k_ws  + (size_t)bh * NKP * HD;   // [key][64]
  const uint16_t* vb = vt_ws + (size_t)bh * HD * NKP;   // [d][NKP]

  f32x4 acca[4] = {}, accb[4] = {};
  float lsa = 0.f, lsb = 0.f;

  for (int t = 0; t < NTILE; ++t) {
    const int t0 = t * 64;
    // S^T = K Q^T per 16-key chunk; p = exp2(s); pack pairs; stage to ldsp[q][key]
#pragma unroll
    for (int c = 0; c < 4; ++c) {
      const uint16_t* krow = kb + (size_t)(t0 + c * 16 + lr) * HD;
      bf16x8 kf0 = *(const bf16x8*)(krow + lg * 8);
      bf16x8 kf1 = *(const bf16x8*)(krow + 32 + lg * 8);
      f32x4 sa = {}, sb = {};
      sa = __builtin_amdgcn_mfma_f32_16x16x32_bf16(kf0, qfa[0], sa, 0, 0, 0);
      sa = __builtin_amdgcn_mfma_f32_16x16x32_bf16(kf1, qfa[1], sa, 0, 0, 0);
      sb = __builtin_amdgcn_mfma_f32_16x16x32_bf16(kf0, qfb[0], sb, 0, 0, 0);
      sb = __builtin_amdgcn_mfma_f32_16x16x32_bf16(kf1, qfb[1], sb, 0, 0, 0);
      float p0 = exp2f(sa[0]), p1 = exp2f(sa[1]);
      float p2 = exp2f(sa[2]), p3 = exp2f(sa[3]);
      lsa += (p0 + p1) + (p2 + p3);
      *(uint32_t*)&ldsp[0][lr][c * 16 + lg * 4]     = pack2(p0, p1);
      *(uint32_t*)&ldsp[0][lr][c * 16 + lg * 4 + 2] = pack2(p2, p3);
      p0 = exp2f(sb[0]); p1 = exp2f(sb[1]);
      p2 = exp2f(sb[2]); p3 = exp2f(sb[3]);
      lsb += (p0 + p1) + (p2 + p3);
      *(uint32_t*)&ldsp[1][lr][c * 16 + lg * 4]     = pack2(p0, p1);
      *(uint32_t*)&ldsp[1][lr][c * 16 + lg * 4 + 2] = pack2(p2, p3);
    }
    // fence 1: u32 LDS writes -> bf16x8 LDS reads (same wave, distinct TBAA types)
    asm volatile("" ::: "memory");
    __builtin_amdgcn_sched_barrier(0);

    // O += P V : A = P[q=lr][k], B = V^T[key][d] from global (L2-resident)
#pragma unroll
    for (int kk = 0; kk < 2; ++kk) {
      bf16x8 pfa = *(const bf16x8*)&ldsp[0][lr][kk * 32 + lg * 8];
      bf16x8 pfb = *(const bf16x8*)&ldsp[1][lr][kk * 32 + lg * 8];
#pragma unroll
      for (int cd = 0; cd < 4; ++cd) {
        bf16x8 vf = *(const bf16x8*)(vb + (size_t)(cd * 16 + lr) * NKP + t0 + kk * 32 + lg * 8);
        acca[cd] = __builtin_amdgcn_mfma_f32_16x16x32_bf16(pfa, vf, acca[cd], 0, 0, 0);
        accb[cd] = __builtin_amdgcn_mfma_f32_16x16x32_bf16(pfb, vf, accb[cd], 0, 0, 0);
      }
    }
    // fence 2: this tile's bf16x8 reads -> next tile's u32 writes (WAR on ldsp)
    asm volatile("" ::: "memory");
    __builtin_amdgcn_sched_barrier(0);
  }

  // l for q=lr: reduce over lg groups; route to output rows (q=lg*4+r) via shfl
  lsa += __shfl_xor(lsa, 16); lsa += __shfl_xor(lsa, 32);
  lsb += __shfl_xor(lsb, 16); lsb += __shfl_xor(lsb, 32);

#pragma unroll
  for (int r = 0; r < 4; ++r) {
    const int src = lg * 4 + r;                    // lane holding l for this out row
    const float inva = 1.0f / (__shfl(lsa, src) - 63.0f);
    const float invb = 1.0f / (__shfl(lsb, src) - 63.0f);
    const int na = qrow0 + lg * 4 + r;
    size_t basea = ((size_t)b * NN + na) * DIMF + h * HD;
    size_t baseb = basea + (size_t)16 * DIMF;
#pragma unroll
    for (int cd = 0; cd < 4; ++cd) {
      o_ws[basea + cd * 16 + lr] = f2b(acca[cd][r] * inva);
      o_ws[baseb + cd * 16 + lr] = f2b(accb[cd][r] * invb);
    }
  }
}

extern "C" void kernel_launch(void* const* d_in, const int* in_sizes, int n_in,
                              void* d_out, int out_size, void* d_ws, size_t ws_size,
                              hipStream_t stream) {
  const float* x      = (const float*)d_in[0];
  const float* wqkv   = (const float*)d_in[1];
  const float* wout   = (const float*)d_in[2];
  const float* bout   = (const float*)d_in[3];
  // d_in[4] = void_q: unused (void query row is dropped by the reference)
  const float* voidk  = (const float*)d_in[5];
  const float* voidv  = (const float*)d_in[6];
  const float* trace  = (const float*)d_in[7];
  const float* factor = (const float*)d_in[8];
  float* out = (float*)d_out;           // reference output dtype is FP32

  uint16_t* ws    = (uint16_t*)d_ws;
  uint16_t* x_bf  = ws;                       // 2*2048*1024  = 4,194,304 elems
  uint16_t* o_ws  = x_bf;                     // ALIAS: x_bf dead after gemm<0>
  uint16_t* wqkvT = x_bf  + 4194304;          // 3072*1024    = 3,145,728
  uint16_t* woutT = wqkvT + 3145728;          // 1024*1024    = 1,048,576
  uint16_t* q_ws  = woutT + 1048576;          // 2*16*2048*64 = 4,194,304
  uint16_t* k_ws  = q_ws  + 4194304;          // 2*16*2112*64 = 4,325,376
  uint16_t* vt_ws = k_ws  + 4325376;          // 4,325,376   (total ~42.5 MB)

  cvt_f32_bf16<<<dim3(4194304 / 4 / 256), dim3(256), 0, stream>>>(x, x_bf, 4194304 / 4);
  transpose_k<<<dim3(3072 / 32, 1024 / 32), dim3(32, 8), 0, stream>>>(wqkv, wqkvT, 1024, 3072);
  transpose_k<<<dim3(1024 / 32, 1024 / 32), dim3(32, 8), 0, stream>>>(wout, woutT, 1024, 1024);
  fill_void<<<dim3(512), dim3(256), 0, stream>>>(voidk, voidv, k_ws, vt_ws);
  gemm_bt<0><<<dim3(3072 / 128, 4096 / 128), dim3(256), 0, stream>>>(
      x_bf, wqkvT, 1024, 3072, q_ws, k_ws, vt_ws, nullptr, nullptr, trace, factor);
  attn_g<<<dim3(HEADS * BB, NN / 32), dim3(64), 0, stream>>>(q_ws, k_ws, vt_ws, o_ws);
  gemm_bt<1><<<dim3(1024 / 128, 4096 / 128), dim3(256), 0, stream>>>(
      o_ws, woutT, 1024, 1024, nullptr, nullptr, nullptr, out, bout, nullptr, nullptr);
}

// Round 10
// 177.328 us; speedup vs baseline: 1.2807x; 1.2807x over previous
//
#include <hip/hip_runtime.h>
#include <hip/hip_bf16.h>
#include <stdint.h>

#define DIMF   1024
#define HEADS  16
#define HD     64
#define BB     2
#define NN     2048
#define NKP    2112   // 2049 keys padded to 33*64
#define NTILE  33

typedef __attribute__((ext_vector_type(8))) __bf16 bf16x8;
typedef __attribute__((ext_vector_type(4))) float  f32x4;

__device__ __forceinline__ float b2f(uint16_t h) {
  union { uint32_t u; float f; } v; v.u = ((uint32_t)h) << 16; return v.f;
}
__device__ __forceinline__ uint16_t f2b(float f) {
  union { float f; uint32_t u; } v; v.f = f;
  uint32_t r = v.u + 0x7FFFu + ((v.u >> 16) & 1u);
  return (uint16_t)(r >> 16);
}
// packed f32x2 -> bf16x2 via the COMPILER intrinsic (operand order guaranteed;
// round-8 HW-verified: low half = first arg)
__device__ __forceinline__ uint32_t pack2(float a, float b) {
  __hip_bfloat162 h = __float22bfloat162_rn(float2{a, b});
  union { __hip_bfloat162 h; uint32_t u; } v; v.h = h; return v.u;
}

// async global->LDS DMA, 16B per lane. LDS dest = wave-uniform base + lane*16.
__device__ __forceinline__ void gl_lds16(const void* g, void* l) {
  __builtin_amdgcn_global_load_lds(
      (const __attribute__((address_space(1))) void*)g,
      (__attribute__((address_space(3))) void*)l, 16, 0, 0);
}

// ---------------- fp32 -> bf16 bulk convert (float4 loads) ----------------
__global__ __launch_bounds__(256) void cvt_f32_bf16(const float* __restrict__ src,
                                                    uint16_t* __restrict__ dst, int n4) {
  int i = blockIdx.x * 256 + threadIdx.x;
  if (i < n4) {
    float4 v = *(const float4*)&src[i * 4];
    uint16_t* d = dst + i * 4;
    d[0] = f2b(v.x); d[1] = f2b(v.y); d[2] = f2b(v.z); d[3] = f2b(v.w);
  }
}

// -------- transpose + convert (fp32 M x N -> bf16 N x M), 32x32 tiles --------
__global__ __launch_bounds__(256) void transpose_k(const float* __restrict__ src,
                                                   uint16_t* __restrict__ dst, int M, int N) {
  __shared__ uint16_t tile[32][33];
  int bx = blockIdx.x * 32, by = blockIdx.y * 32;
  int x = threadIdx.x, y0 = threadIdx.y;
#pragma unroll
  for (int i = 0; i < 32; i += 8)
    tile[y0 + i][x] = f2b(src[(size_t)(by + y0 + i) * N + bx + x]);
  __syncthreads();
#pragma unroll
  for (int i = 0; i < 32; i += 8)
    dst[(size_t)(bx + y0 + i) * M + by + x] = tile[x][y0 + i];
}

// ---------------- fill void K/V rows + zero padding ----------------
__global__ __launch_bounds__(256) void fill_void(const float* __restrict__ vk,
                                                 const float* __restrict__ vv,
                                                 uint16_t* __restrict__ k_ws,
                                                 uint16_t* __restrict__ vt_ws) {
  int idx = blockIdx.x * 256 + threadIdx.x;   // 0 .. 131071 = BB*HEADS*64*64
  int dd = idx & 63;
  int r  = (idx >> 6) & 63;      // padded key row 2048+r
  int bh = idx >> 12;            // 0..31
  int h  = bh & (HEADS - 1);
  uint16_t kv  = (r == 0) ? f2b(vk[h * HD + dd]) : (uint16_t)0;
  uint16_t vvv = (r == 0) ? f2b(vv[h * HD + dd]) : (uint16_t)0;
  k_ws[((size_t)bh * NKP + NN + r) * HD + dd]  = kv;
  vt_ws[((size_t)bh * HD + dd) * NKP + NN + r] = vvv;
}

// ---------------- GEMM: C[M,N] = A[M,K] * Bt[N,K]^T, bf16 in, fp32 acc ----------------
// EPI 0: scatter bf16 to Q [bh,2048,64] (PRE-SCALED by per-head scale*log2e),
//        K [bh,2112,64], Vt [bh,64,2112]
// EPI 1: add fp32 bias, write FP32 row-major [M,Nout] (d_out is float*)
template<int EPI>
__global__ __launch_bounds__(256) void gemm_bt(const uint16_t* __restrict__ A,
                                               const uint16_t* __restrict__ Bt,
                                               int K, int Nout,
                                               uint16_t* __restrict__ o0,
                                               uint16_t* __restrict__ o1,
                                               uint16_t* __restrict__ o2,
                                               float* __restrict__ fo,
                                               const float* __restrict__ bias,
                                               const float* __restrict__ trace,
                                               const float* __restrict__ factor) {
  __shared__ uint16_t lds_a[128][32];   // linear: required by global_load_lds
  __shared__ uint16_t lds_b[128][32];
  const int m0 = blockIdx.y * 128, n0 = blockIdx.x * 128;
  const int tid = threadIdx.x, lane = tid & 63, wid = tid >> 6;
  const int wm = (wid >> 1) * 64, wn = (wid & 1) * 64;
  const int lr = lane & 15, lg = lane >> 4;
  f32x4 acc[4][4] = {};
  for (int k0 = 0; k0 < K; k0 += 32) {
    __syncthreads();
#pragma unroll
    for (int it = 0; it < 2; ++it) {
      const int chunk = wid * 2 + it;            // 0..7 (1 KiB each)
      const int o = chunk * 1024 + lane * 16;
      const int r = o >> 6, cb = o & 63;
      gl_lds16((const char*)&A[(size_t)(m0 + r) * K + k0] + cb,
               (char*)&lds_a[0][0] + chunk * 1024);
      gl_lds16((const char*)&Bt[(size_t)(n0 + r) * K + k0] + cb,
               (char*)&lds_b[0][0] + chunk * 1024);
    }
    __syncthreads();
    bf16x8 af[4], bf[4];
#pragma unroll
    for (int i = 0; i < 4; ++i)
      af[i] = *(const bf16x8*)((const char*)&lds_a[0][0] + (wm + i * 16 + lr) * 64 + lg * 16);
#pragma unroll
    for (int j = 0; j < 4; ++j)
      bf[j] = *(const bf16x8*)((const char*)&lds_b[0][0] + (wn + j * 16 + lr) * 64 + lg * 16);
#pragma unroll
    for (int i = 0; i < 4; ++i)
#pragma unroll
      for (int j = 0; j < 4; ++j)
        acc[i][j] = __builtin_amdgcn_mfma_f32_16x16x32_bf16(af[i], bf[j], acc[i][j], 0, 0, 0);
  }
#pragma unroll
  for (int i = 0; i < 4; ++i)
#pragma unroll
    for (int j = 0; j < 4; ++j)
#pragma unroll
      for (int r = 0; r < 4; ++r) {
        int mg = m0 + wm + i * 16 + lg * 4 + r;   // C row = m (m89 layout)
        int ng = n0 + wn + j * 16 + lr;            // C col = n
        float v = acc[i][j][r];
        if (EPI == 0) {
          int b = mg >> 11, n = mg & (NN - 1);
          int which = ng >> 10, rem = ng & (DIMF - 1), h = rem >> 6, dd = rem & 63;
          int bh = b * HEADS + h;
          float vv = v;
          if (which == 0) {   // Q: fold (dim^-0.5 / temp) * log2(e) into Q
            float tmp = fmaxf(1.0f + fabsf(trace[h]) * factor[h], 1.0f);
            vv = v * (0.04508422f / tmp);          // 0.03125 * 1.44269504
          }
          uint16_t bv = f2b(vv);
          if (which == 0)      o0[((size_t)bh * NN + n) * HD + dd] = bv;
          else if (which == 1) o1[((size_t)bh * NKP + n) * HD + dd] = bv;
          else                 o2[((size_t)bh * HD + dd) * NKP + n] = bv;  // V transposed
        } else {
          fo[(size_t)mg * Nout + ng] = v + bias[ng];   // FP32 output
        }
      }
}

// -------- flash attention: round-6 shell + swapped QK^T + in-register P pack --------
// 4 waves x 16 q-rows; K/V single-buffered in LDS via global_load_lds, XOR-swizzled
// reads (T2/G21). S^T = mfma(K, Q): lane (lg,lr) holds P[key=c*16+lg*4+r][q=lr] ->
// key-adjacent register pairs -> pack2 + u32 ds_write (8 writes/tile vs 16 b16).
// Q is PRE-SCALED by scale*log2e in gemm<0>, so p = exp2f(s). Fixed-max softmax
// (|logit*log2e| <= ~3); zero-padded phantom keys give p=1, subtracted at end.
// PV = mfma(P, V^T) identical to the round-6/8 proven pattern.
__global__ __launch_bounds__(256) void attn_k(const uint16_t* __restrict__ q_ws,
                                              const uint16_t* __restrict__ k_ws,
                                              const uint16_t* __restrict__ vt_ws,
                                              uint16_t* __restrict__ o_ws) {
  __shared__ uint16_t ldsk[64][64];      // [key][d], swizzled cols (8 KB)
  __shared__ uint16_t ldsv[64][64];      // [d][key], swizzled cols (8 KB)
  __shared__ uint16_t ldsp[4][16][72];   // [wave][q][key(+pad)]     (9.2 KB)
  const int qb = blockIdx.x, h = blockIdx.y, b = blockIdx.z;
  const int bh = b * HEADS + h;
  const int tid = threadIdx.x, lane = tid & 63, wid = tid >> 6;
  const int lr = lane & 15, lg = lane >> 4;

  const int qrow0 = qb * 64 + wid * 16;
  const uint16_t* qp = q_ws + ((size_t)bh * NN + qrow0 + lr) * HD;
  bf16x8 qf[2];
  qf[0] = *(const bf16x8*)(qp + lg * 8);
  qf[1] = *(const bf16x8*)(qp + 32 + lg * 8);

  f32x4 acc[4] = {};
  float lsum = 0.f;

  for (int t = 0; t < NTILE; ++t) {
    const int t0 = t * 64;
    __syncthreads();                       // prev-tile reads done before overwrite
#pragma unroll
    for (int it = 0; it < 2; ++it) {
      const int chunk = wid * 2 + it;      // 0..7 (1 KiB each)
      const int o = chunk * 1024 + lane * 16;
      const int r = o >> 7, cb = o & 127;  // 128 B per row
      const int scb = cb ^ ((r & 7) << 4); // pre-swizzled source col
      gl_lds16((const char*)&k_ws[((size_t)bh * NKP + t0 + r) * HD] + scb,
               (char*)&ldsk[0][0] + chunk * 1024);
      gl_lds16((const char*)&vt_ws[((size_t)bh * HD + r) * NKP + t0] + scb,
               (char*)&ldsv[0][0] + chunk * 1024);
    }
    __syncthreads();                       // DMA drained: tile visible

    // S^T = K Q^T per 16-key chunk; p = exp2(s); pack pairs; stage ldsp[q][key]
#pragma unroll
    for (int c = 0; c < 4; ++c) {
      const int row = c * 16 + lr;
      const int rsw = (row & 7) << 4;
      bf16x8 kf0 = *(const bf16x8*)((const char*)&ldsk[0][0] + row * 128 + ((lg * 16) ^ rsw));
      bf16x8 kf1 = *(const bf16x8*)((const char*)&ldsk[0][0] + row * 128 + ((64 + lg * 16) ^ rsw));
      f32x4 s = {};
      s = __builtin_amdgcn_mfma_f32_16x16x32_bf16(kf0, qf[0], s, 0, 0, 0);
      s = __builtin_amdgcn_mfma_f32_16x16x32_bf16(kf1, qf[1], s, 0, 0, 0);
      float p0 = exp2f(s[0]), p1 = exp2f(s[1]);
      float p2 = exp2f(s[2]), p3 = exp2f(s[3]);
      lsum += (p0 + p1) + (p2 + p3);
      *(uint32_t*)&ldsp[wid][lr][c * 16 + lg * 4]     = pack2(p0, p1);
      *(uint32_t*)&ldsp[wid][lr][c * 16 + lg * 4 + 2] = pack2(p2, p3);
    }
    // ordering fence: u32 LDS writes -> bf16x8 LDS reads, same wave, no barrier
    asm volatile("" ::: "memory");
    __builtin_amdgcn_sched_barrier(0);

    // O += P V : A = P[q=lr... rows][k], B = V^T[key][d] (proven pattern)
#pragma unroll
    for (int kk = 0; kk < 2; ++kk) {
      bf16x8 pf = *(const bf16x8*)&ldsp[wid][lr][kk * 32 + lg * 8];
#pragma unroll
      for (int cd = 0; cd < 4; ++cd) {
        const int row = cd * 16 + lr;
        const int cbb = (kk * 64 + lg * 16) ^ ((row & 7) << 4);
        bf16x8 vf = *(const bf16x8*)((const char*)&ldsv[0][0] + row * 128 + cbb);
        acc[cd] = __builtin_amdgcn_mfma_f32_16x16x32_bf16(pf, vf, acc[cd], 0, 0, 0);
      }
    }
  }

  // l for q=lr (partial over lg's key groups): reduce over lg; route via shfl
  lsum += __shfl_xor(lsum, 16); lsum += __shfl_xor(lsum, 32);

#pragma unroll
  for (int r = 0; r < 4; ++r) {
    const int src = lg * 4 + r;                    // lane holding l for this out row
    const float inv = 1.0f / (__shfl(lsum, src) - 63.0f);
    const int na = qrow0 + lg * 4 + r;             // O row q = lg*4+r
    size_t base = ((size_t)b * NN + na) * DIMF + h * HD;
#pragma unroll
    for (int cd = 0; cd < 4; ++cd)
      o_ws[base + cd * 16 + lr] = f2b(acc[cd][r] * inv);
  }
}

extern "C" void kernel_launch(void* const* d_in, const int* in_sizes, int n_in,
                              void* d_out, int out_size, void* d_ws, size_t ws_size,
                              hipStream_t stream) {
  const float* x      = (const float*)d_in[0];
  const float* wqkv   = (const float*)d_in[1];
  const float* wout   = (const float*)d_in[2];
  const float* bout   = (const float*)d_in[3];
  // d_in[4] = void_q: unused (void query row is dropped by the reference)
  const float* voidk  = (const float*)d_in[5];
  const float* voidv  = (const float*)d_in[6];
  const float* trace  = (const float*)d_in[7];
  const float* factor = (const float*)d_in[8];
  float* out = (float*)d_out;           // reference output dtype is FP32

  uint16_t* ws    = (uint16_t*)d_ws;
  uint16_t* x_bf  = ws;                       // 2*2048*1024  = 4,194,304 elems
  uint16_t* o_ws  = x_bf;                     // ALIAS: x_bf dead after gemm<0>
  uint16_t* wqkvT = x_bf  + 4194304;          // 3072*1024    = 3,145,728
  uint16_t* woutT = wqkvT + 3145728;          // 1024*1024    = 1,048,576
  uint16_t* q_ws  = woutT + 1048576;          // 2*16*2048*64 = 4,194,304
  uint16_t* k_ws  = q_ws  + 4194304;          // 2*16*2112*64 = 4,325,376
  uint16_t* vt_ws = k_ws  + 4325376;          // 4,325,376   (total ~42.5 MB)

  cvt_f32_bf16<<<dim3(4194304 / 4 / 256), dim3(256), 0, stream>>>(x, x_bf, 4194304 / 4);
  transpose_k<<<dim3(3072 / 32, 1024 / 32), dim3(32, 8), 0, stream>>>(wqkv, wqkvT, 1024, 3072);
  transpose_k<<<dim3(1024 / 32, 1024 / 32), dim3(32, 8), 0, stream>>>(wout, woutT, 1024, 1024);
  fill_void<<<dim3(512), dim3(256), 0, stream>>>(voidk, voidv, k_ws, vt_ws);
  gemm_bt<0><<<dim3(3072 / 128, 4096 / 128), dim3(256), 0, stream>>>(
      x_bf, wqkvT, 1024, 3072, q_ws, k_ws, vt_ws, nullptr, nullptr, trace, factor);
  attn_k<<<dim3(NN / 64, HEADS, BB), dim3(256), 0, stream>>>(q_ws, k_ws, vt_ws, o_ws);
  gemm_bt<1><<<dim3(1024 / 128, 4096 / 128), dim3(256), 0, stream>>>(
      o_ws, woutT, 1024, 1024, nullptr, nullptr, nullptr, out, bout, nullptr, nullptr);
}